// Round 2
// baseline (652.531 us; speedup 1.0000x reference)
//
#include <hip/hip_runtime.h>
#include <hip/hip_bf16.h>
#include <stdint.h>

#define VOCAB 50257
#define VPAD  50432   /* 197*256 */
#define DIM   640
#define SEQ   256
#define NBATCH 16
#define MROWS 4096    /* NBATCH*SEQ */
#define NTILES 10     /* DIM/64 */

using bf16 = __hip_bfloat16;
typedef __attribute__((ext_vector_type(8))) short short8;
typedef __attribute__((ext_vector_type(4))) float f32x4;

__device__ __forceinline__ void gld_lds16(const void* g, void* l) {
  __builtin_amdgcn_global_load_lds(
      (const __attribute__((address_space(1))) void*)g,
      (__attribute__((address_space(3))) void*)l, 16, 0, 0);
}

#define BAR() asm volatile("s_barrier" ::: "memory")
#define VMC(n) asm volatile("s_waitcnt vmcnt(" #n ")" ::: "memory")

// ---------------- embed: x = w_embed[idx] + w_pos  -> bf16 ----------------
__global__ void embed_kernel(const int* __restrict__ idx,
                             const float* __restrict__ we,
                             const float* __restrict__ wp,
                             bf16* __restrict__ xb) {
  int row = blockIdx.x;
  int t = row & (SEQ - 1);
  int tok = idx[row];
  const float* src = we + (long)tok * DIM;
  const float* pos = wp + (long)t * DIM;
  for (int d = threadIdx.x; d < DIM; d += blockDim.x)
    xb[(long)row * DIM + d] = __float2bfloat16(src[d] + pos[d]);
}

// ---------------- f32 -> bf16 convert with zero tail pad ----------------
__global__ void conv_kernel(const float* __restrict__ src, bf16* __restrict__ dst,
                            long n_src, long n_dst) {
  long i = (long)blockIdx.x * blockDim.x + threadIdx.x;
  long stride = (long)gridDim.x * blockDim.x;
  for (; i < n_dst; i += stride)
    dst[i] = __float2bfloat16(i < n_src ? src[i] : 0.f);
}

// ---------------- v (16*256,640) -> vT (16,640,256) ----------------
__global__ void transpose_v(const bf16* __restrict__ v, bf16* __restrict__ vt) {
  long i = (long)blockIdx.x * blockDim.x + threadIdx.x;
  if (i >= (long)NBATCH * DIM * SEQ) return;
  int t = (int)(i & (SEQ - 1));
  long be = i >> 8;
  int e = (int)(be % DIM);
  int b = (int)(be / DIM);
  vt[i] = v[((long)b * SEQ + t) * DIM + e];
}

// ---------------- causal softmax: scores f32 -> P bf16 ----------------
__global__ void softmax_kernel(const float* __restrict__ sc, bf16* __restrict__ p) {
  int wid = threadIdx.x >> 6, lane = threadIdx.x & 63;
  int row = blockIdx.x * 4 + wid;
  int t = row & (SEQ - 1);
  const float* srow = sc + (long)row * SEQ;
  const float rsc = 0.03952847075210474f;  // 1/sqrt(640)
  float v[4];
  float mx = -1e30f;
#pragma unroll
  for (int i = 0; i < 4; ++i) {
    int s = lane + 64 * i;
    v[i] = (s <= t) ? srow[s] * rsc : -1e30f;
    mx = fmaxf(mx, v[i]);
  }
#pragma unroll
  for (int off = 32; off; off >>= 1) mx = fmaxf(mx, __shfl_xor(mx, off, 64));
  float sum = 0.f;
#pragma unroll
  for (int i = 0; i < 4; ++i) {
    int s = lane + 64 * i;
    v[i] = (s <= t) ? __expf(v[i] - mx) : 0.f;
    sum += v[i];
  }
#pragma unroll
  for (int off = 32; off; off >>= 1) sum += __shfl_xor(sum, off, 64);
  float inv = 1.f / sum;
#pragma unroll
  for (int i = 0; i < 4; ++i)
    p[(long)row * SEQ + lane + 64 * i] = __float2bfloat16(v[i] * inv);
}

// ---------------- generic C = A * B^T  (m97-style 128x128 tile) ----------------
template <typename OUT_T, bool BIAS>
__global__ __launch_bounds__(256, 2) void gemm_bt(
    const bf16* __restrict__ Ag, const bf16* __restrict__ Bg,
    OUT_T* __restrict__ Cg, const float* __restrict__ bias,
    int K, int ldc, int Nstore, long sA, long sB, long sC) {
  __shared__ bf16 As[128 * 32];
  __shared__ bf16 Bs[128 * 32];
  const int tid = threadIdx.x;
  const int wv = tid >> 6, lane = tid & 63;
  const int tm = blockIdx.x * 128, tn = blockIdx.y * 128;
  const int bz = blockIdx.z;
  const bf16* A = Ag + (long)bz * sA + (long)tm * K;
  const bf16* B = Bg + (long)bz * sB + (long)tn * K;

  f32x4 acc[4][4] = {};
  const int wr = (wv >> 1) * 64, wc = (wv & 1) * 64;
  const int lr = lane & 15, lk = (lane >> 4) * 8;
  const int srow0 = wv * 32;
  const int g_r = lane >> 2, g_k = (lane & 3) * 8;

  for (int k0 = 0; k0 < K; k0 += 32) {
#pragma unroll
    for (int j = 0; j < 2; ++j) {
      int r = srow0 + j * 16;
      gld_lds16(A + (long)(r + g_r) * K + k0 + g_k, &As[r * 32]);
      gld_lds16(B + (long)(r + g_r) * K + k0 + g_k, &Bs[r * 32]);
    }
    __syncthreads();
    short8 a[4], b[4];
#pragma unroll
    for (int m = 0; m < 4; ++m)
      a[m] = *(const short8*)&As[(wr + m * 16 + lr) * 32 + lk];
#pragma unroll
    for (int n = 0; n < 4; ++n)
      b[n] = *(const short8*)&Bs[(wc + n * 16 + lr) * 32 + lk];
#pragma unroll
    for (int m = 0; m < 4; ++m)
#pragma unroll
      for (int n = 0; n < 4; ++n)
        acc[m][n] = __builtin_amdgcn_mfma_f32_16x16x32_bf16(a[m], b[n], acc[m][n], 0, 0, 0);
    __syncthreads();
  }

  OUT_T* C = Cg + (long)bz * sC;
  const int crow0 = tm + wr + (lane >> 4) * 4;
  const int ccol0 = tn + wc + (lane & 15);
#pragma unroll
  for (int m = 0; m < 4; ++m)
#pragma unroll
    for (int n = 0; n < 4; ++n) {
      int col = ccol0 + n * 16;
      if (col < Nstore) {
        float bv = BIAS ? bias[col] : 0.f;
#pragma unroll
        for (int j = 0; j < 4; ++j) {
          long row = crow0 + m * 16 + j;
          float val = acc[m][n][j] + bv;
          if constexpr (sizeof(OUT_T) == 2)
            C[row * ldc + col] = __float2bfloat16(val);
          else
            C[row * ldc + col] = val;
        }
      }
    }
}

// ================= 256x256 8-phase GEMM: C = A * B^T + bias =================
// A: (4096, 640) bf16; B: (50432, 640) bf16 (zero-padded); C: (4096, VOCAB) f32.
// BK=64, 8 waves (2M x 4N), 128 KiB LDS dbuf, st_16x32 XOR swizzle,
// counted vmcnt(6), raw s_barrier, setprio around MFMA clusters.
// Per K-tile: 4 phases. Issue order: p0:B1(T+1) p1:B0(T+2) p2:A0(T+2) p3:A1(T+2)+vmcnt(6).
// Reads: A(mh0)+B(both ks) @p0, A(mh1) @p1 -> every overwrite targets a
// region whose reads finished >=1 barrier earlier.
__global__ __launch_bounds__(512, 1) void gemm256(
    const bf16* __restrict__ Ag, const bf16* __restrict__ Bg,
    float* __restrict__ Cg, const float* __restrict__ bias) {
  __shared__ __align__(16) char lds[131072];
  const int tid = threadIdx.x;
  const int lane = tid & 63, wv = tid >> 6;
  const int wm = wv >> 2, wn = wv & 3;

  // T1: XCD-aware bijective swizzle (3152 % 8 == 0), M-fastest for B-tile reuse
  int bid = blockIdx.x;
  int swz = (bid & 7) * 394 + (bid >> 3);
  const int tm = swz & 15, tn = swz >> 4;

  // staging: per-thread source offsets with st_16x32 swizzle pre-applied.
  // LDS half layout: byte L = kk*8192 + r*64 + c2 ; sigma(L) = L ^ ((L>>9 &1)<<5)
  int e0, e1, du0, du1;
  {
    int L0 = tid * 16;
    int L1 = (512 + tid) * 16;
    int Lp0 = L0 ^ (((L0 >> 9) & 1) << 5);
    int Lp1 = L1 ^ (((L1 >> 9) & 1) << 5);
    e0 = ((Lp0 >> 6) & 127) * DIM + ((Lp0 >> 13) & 1) * 32 + ((Lp0 & 63) >> 1);
    e1 = ((Lp1 >> 6) & 127) * DIM + ((Lp1 >> 13) & 1) * 32 + ((Lp1 & 63) >> 1);
    du0 = (wv << 6) * 16;           // wave-uniform dest (HW adds lane*16)
    du1 = (512 + (wv << 6)) * 16;
  }
  auto STAGE = [&](int halfBase, const bf16* src) {
    gld_lds16(src + e0, lds + halfBase + du0);
    gld_lds16(src + e1, lds + halfBase + du1);
  };

  const bf16* Abase = Ag + (long)tm * 256 * DIM;
  const bf16* Bbase = Bg + (long)tn * 256 * DIM;

  // ds_read addressing (swizzled): lane offset constant per lane
  const int lr = lane & 15, h16 = lane >> 4;
  const int laneOff = (lr * 64 + h16 * 16) ^ ((lr & 8) << 2);
  const int abase = wm * 16384 + laneOff;
  const int bbase = 32768 + (wn >> 1) * 16384 + (wn & 1) * 4096 + laneOff;

  f32x4 acc[8][4] = {};
  short8 a0[2][4], a1[2][4], b[2][4];

#define READ_A(DST, SLOT, MFB)                                                \
  { _Pragma("unroll") for (int ks = 0; ks < 2; ++ks)                          \
    _Pragma("unroll") for (int mf = 0; mf < 4; ++mf)                          \
      DST[ks][mf] = *(const short8*)(lds + (SLOT) + abase + ks * 8192 +       \
                                     ((MFB) + mf) * 1024); }
#define READ_B(SLOT)                                                          \
  { _Pragma("unroll") for (int ks = 0; ks < 2; ++ks)                          \
    _Pragma("unroll") for (int nf = 0; nf < 4; ++nf)                          \
      b[ks][nf] = *(const short8*)(lds + (SLOT) + bbase + ks * 8192 +         \
                                   nf * 1024); }
#define MFMA_G(AARR, KS, ROFF)                                                \
  __builtin_amdgcn_s_setprio(1);                                              \
  { _Pragma("unroll") for (int mf = 0; mf < 4; ++mf)                          \
    _Pragma("unroll") for (int nf = 0; nf < 4; ++nf)                          \
      acc[(ROFF) + mf][nf] = __builtin_amdgcn_mfma_f32_16x16x32_bf16(         \
          AARR[KS][mf], b[KS][nf], acc[(ROFF) + mf][nf], 0, 0, 0); }          \
  __builtin_amdgcn_s_setprio(0);

  // ---- prologue: tile0 (all 4 halves) + tile1 {B0, A0, A1}; vmcnt(6) keeps
  // the last 3 in flight while guaranteeing tile0 landed.
  STAGE(0,             Abase);
  STAGE(16384,         Abase + 128 * DIM);
  STAGE(32768,         Bbase);
  STAGE(49152,         Bbase + 128 * DIM);
  STAGE(65536 + 32768, Bbase + 64);
  STAGE(65536 + 0,     Abase + 64);
  STAGE(65536 + 16384, Abase + 128 * DIM + 64);
  VMC(6);
  BAR();

#pragma unroll
  for (int T = 0; T < NTILES; ++T) {
    const int slot = (T & 1) << 16;
    const int nslot = ((T + 1) & 1) << 16;
    // ---- phase 0: read A(mh0) both ks + B both ks; stage B1(T+1)
    READ_A(a0, slot, 0);
    READ_B(slot);
    if (T + 1 < NTILES) STAGE(nslot + 49152, Bbase + 128 * DIM + (T + 1) * 64);
    BAR();
    MFMA_G(a0, 0, 0);
    BAR();
    // ---- phase 1: read A(mh1); stage A0(T+2) (region read-complete @p0... A: p0-p1; A0 region = rows 0-127 read by wm0 waves at p0&p1 -> issue after p1? No: A0 reads end at p1; issue here is AFTER p0 barrier, arrival gated only by landing -- issue must be after last READ of region. A(mh0/mh1) are both in wave's own half; region A0 = wm0 waves' reads at p0 AND p1. So A0 stage belongs at p2. B0 here instead.
    READ_A(a1, slot, 4);
    if (T + 2 < NTILES) STAGE(slot + 32768, Bbase + (T + 2) * 64);  // B0: reads done @p0
    BAR();
    MFMA_G(a0, 1, 0);
    BAR();
    // ---- phase 2: stage A0(T+2) (A reads done @p1)
    if (T + 2 < NTILES) STAGE(slot + 0, Abase + (T + 2) * 64);
    BAR();
    MFMA_G(a1, 0, 4);
    BAR();
    // ---- phase 3: stage A1(T+2); counted vmcnt
    if (T + 2 < NTILES) {
      STAGE(slot + 16384, Abase + 128 * DIM + (T + 2) * 64);
      VMC(6);
    } else if (T + 1 < NTILES) {
      VMC(0);
    }
    BAR();
    MFMA_G(a1, 1, 4);
    BAR();
  }
#undef READ_A
#undef READ_B
#undef MFMA_G

  // ---- epilogue: C write + bias, masked to col < VOCAB
  const int rowB = tm * 256 + wm * 128 + h16 * 4;
  const int colB = tn * 256 + wn * 64 + lr;
#pragma unroll
  for (int mf = 0; mf < 8; ++mf)
#pragma unroll
    for (int nf = 0; nf < 4; ++nf) {
      int col = colB + nf * 16;
      if (col < VOCAB) {
        float bv = bias[col];
#pragma unroll
        for (int jj = 0; jj < 4; ++jj)
          Cg[(long)(rowB + mf * 16 + jj) * VOCAB + col] = acc[mf][nf][jj] + bv;
      }
    }
}

extern "C" void kernel_launch(void* const* d_in, const int* in_sizes, int n_in,
                              void* d_out, int out_size, void* d_ws, size_t ws_size,
                              hipStream_t stream) {
  const int*   idx     = (const int*)d_in[0];
  const float* w_embed = (const float*)d_in[1];
  const float* w_pos   = (const float*)d_in[2];
  const float* wq      = (const float*)d_in[3];
  const float* wk      = (const float*)d_in[4];
  const float* wv      = (const float*)d_in[5];
  const float* w_out   = (const float*)d_in[6];
  const float* b_out   = (const float*)d_in[7];
  float* out = (float*)d_out;

  size_t off = 0;
  auto alloc = [&](size_t bytes) {
    void* p = (char*)d_ws + off;
    off += (bytes + 255) & ~(size_t)255;
    return p;
  };
  bf16* x_bf    = (bf16*)alloc((size_t)MROWS * DIM * 2);
  bf16* wqkv_bf = (bf16*)alloc((size_t)3 * DIM * DIM * 2);
  bf16* wout_bf = (bf16*)alloc((size_t)VPAD * DIM * 2);
  bf16* qkv     = (bf16*)alloc((size_t)3 * MROWS * DIM * 2);
  bf16* vT      = (bf16*)alloc((size_t)NBATCH * DIM * SEQ * 2);
  float* scores = (float*)alloc((size_t)NBATCH * SEQ * SEQ * 4);
  bf16* P       = (bf16*)alloc((size_t)NBATCH * SEQ * SEQ * 2);
  bf16* attn    = (bf16*)alloc((size_t)MROWS * DIM * 2);

  const long QKV_S = (long)MROWS * DIM;
  const long W_S   = (long)DIM * DIM;

  // 1. embed
  embed_kernel<<<MROWS, 256, 0, stream>>>(idx, w_embed, w_pos, x_bf);

  // 2. weight converts (bf16; w_out zero-padded to VPAD rows)
  conv_kernel<<<512, 256, 0, stream>>>(wq, wqkv_bf,           W_S, W_S);
  conv_kernel<<<512, 256, 0, stream>>>(wk, wqkv_bf + W_S,     W_S, W_S);
  conv_kernel<<<512, 256, 0, stream>>>(wv, wqkv_bf + 2 * W_S, W_S, W_S);
  conv_kernel<<<4096, 256, 0, stream>>>(w_out, wout_bf, (long)VOCAB * DIM, (long)VPAD * DIM);

  // 3. q,k,v = x @ {wq,wk,wv}^T
  gemm_bt<bf16, false><<<dim3(MROWS / 128, DIM / 128, 3), 256, 0, stream>>>(
      x_bf, wqkv_bf, qkv, nullptr, DIM, DIM, DIM, 0, W_S, QKV_S);

  // 4. vT per batch
  {
    long n = (long)NBATCH * DIM * SEQ;
    transpose_v<<<(int)((n + 255) / 256), 256, 0, stream>>>(qkv + 2 * QKV_S, vT);
  }

  // 5. scores[b] = q[b] @ k[b]^T
  gemm_bt<float, false><<<dim3(SEQ / 128, SEQ / 128, NBATCH), 256, 0, stream>>>(
      qkv, qkv + QKV_S, scores, nullptr, DIM, SEQ, SEQ,
      (long)SEQ * DIM, (long)SEQ * DIM, (long)SEQ * SEQ);

  // 6. causal softmax -> P bf16
  softmax_kernel<<<MROWS / 4, 256, 0, stream>>>(scores, P);

  // 7. attn[b] = P[b] @ vT[b]^T
  gemm_bt<bf16, false><<<dim3(SEQ / 128, DIM / 128, NBATCH), 256, 0, stream>>>(
      P, vT, attn, nullptr, SEQ, DIM, DIM,
      (long)SEQ * SEQ, (long)DIM * SEQ, (long)SEQ * DIM);

  // 8. logits = attn @ w_out^T + b_out  (256x256 8-phase kernel)
  gemm256<<<16 * 197, 512, 0, stream>>>(attn, wout_bf, out, b_out);
}